// Round 20
// baseline (180.692 us; speedup 1.0000x reference)
//
#include <hip/hip_runtime.h>
#include <hip/hip_bf16.h>

using bf16 = __hip_bfloat16;
typedef __attribute__((ext_vector_type(8))) __bf16 bf16x8;
typedef __attribute__((ext_vector_type(4))) short s16x4;
typedef __attribute__((ext_vector_type(4))) float f32x4;

#define B_   4
#define T_   2048
#define D_   1024
#define H_   16
#define HD_  64
#define BH_  (B_ * H_)
#define BT_  (B_ * T_)

// Q pre-scale: 1/sqrt(64) * log2(e)  -> softmax computed with exp2
#define QSCALE 0.18033688011112042f

__device__ __forceinline__ void gld_lds16(const void* g, void* l) {
    __builtin_amdgcn_global_load_lds(
        (const __attribute__((address_space(1))) unsigned int*)g,
        (__attribute__((address_space(3))) unsigned int*)l,
        16, 0, 0);
}

__device__ __forceinline__ f32x4 mfma16(s16x4 a, s16x4 b, f32x4 c) {
#if defined(__HIP_DEVICE_COMPILE__)
  #if __has_builtin(__builtin_amdgcn_mfma_f32_16x16x16bf16_1k)
    return __builtin_amdgcn_mfma_f32_16x16x16bf16_1k(a, b, c, 0, 0, 0);
  #else
    f32x4 d;
    asm volatile("v_mfma_f32_16x16x16_bf16 %0, %1, %2, %3\n\ts_nop 7\n\ts_nop 7"
                 : "=v"(d) : "v"(a), "v"(b), "v"(c));
    return d;
  #endif
#else
    (void)a; (void)b;
    return c;
#endif
}

__device__ __forceinline__ unsigned bfbits(float x) {
    return (unsigned)__builtin_bit_cast(unsigned short, __float2bfloat16(x));
}

// ---------------------------------------------------------------- fused prep (frozen)
__global__ __launch_bounds__(256)
void prep_kernel(const float* __restrict__ x,
                 const float* __restrict__ W_attn,
                 const float* __restrict__ W_proj,
                 bf16* __restrict__ xh, bf16* __restrict__ WaT, bf16* __restrict__ WpT) {
    __shared__ float tile[32][33];
    const int blk = blockIdx.x;
    const int tid = threadIdx.x;

    if (blk < 4096) {
        const size_t i = ((size_t)blk * 256 + tid) * 8;
        float4 v0 = *reinterpret_cast<const float4*>(x + i);
        float4 v1 = *reinterpret_cast<const float4*>(x + i + 4);
        uint4 p;
        p.x = bfbits(v0.x) | (bfbits(v0.y) << 16);
        p.y = bfbits(v0.z) | (bfbits(v0.w) << 16);
        p.z = bfbits(v1.x) | (bfbits(v1.y) << 16);
        p.w = bfbits(v1.z) | (bfbits(v1.w) << 16);
        *reinterpret_cast<uint4*>(xh + i) = p;
        return;
    }

    if (blk < 4096 + 3072) {
        const int t = blk - 4096;
        const int nb = (t % 96) * 32, kb = (t / 96) * 32;
        const int tx = tid & 31, ty = tid >> 5;
        #pragma unroll
        for (int i = 0; i < 32; i += 8)
            tile[ty + i][tx] = W_attn[(size_t)(kb + ty + i) * 3072 + nb + tx];
        __syncthreads();
        #pragma unroll
        for (int i = 0; i < 32; i += 8)
            WaT[(size_t)(nb + ty + i) * 1024 + kb + tx] = __float2bfloat16(tile[tx][ty + i]);
    } else {
        const int t = blk - 4096 - 3072;
        const int nb = (t % 32) * 32, kb = (t / 32) * 32;
        const int tx = tid & 31, ty = tid >> 5;
        #pragma unroll
        for (int i = 0; i < 32; i += 8)
            tile[ty + i][tx] = W_proj[(size_t)(kb + ty + i) * 1024 + nb + tx];
        __syncthreads();
        #pragma unroll
        for (int i = 0; i < 32; i += 8)
            WpT[(size_t)(nb + ty + i) * 1024 + kb + tx] = __float2bfloat16(tile[tx][ty + i]);
    }
}

// ---------------------------------------------------------------- GEMM (R19 8-wave ring-3, frozen)
template <int MODE>
__global__ __launch_bounds__(512)
void gemm_bt(const bf16* __restrict__ A, const bf16* __restrict__ Bt,
             const float* __restrict__ bias,
             bf16* __restrict__ Qo, bf16* __restrict__ Ko, bf16* __restrict__ Vo,
             float* __restrict__ Fo) {
    constexpr int K = 1024;
    const int bm = blockIdx.x * 128;
    const int bn = blockIdx.y * 128;
    const int tid  = threadIdx.x;
    const int wid  = tid >> 6;
    const int lane = tid & 63;
    const int wr = (wid >> 1) * 32;
    const int wc = (wid & 1) * 64;
    const int ln_g = lane >> 4;
    const int ln_c = lane & 15;

    __shared__ bf16 sm[3][2][128][32];

    f32x4 acc[2][4] = {};

    const int g_row0 = wid * 16 + (lane >> 2);
    const int g_chk  = ((lane & 3) ^ ((lane >> 3) & 3)) * 8;
    const int l_row0 = wid * 16;
    const int colx = (ln_g * 16) ^ (((ln_c >> 1) & 3) << 4);

#define STAGE(S_, T_) {                                                               \
    gld_lds16(&A [(size_t)(bm + g_row0) * K + (T_) * 32 + g_chk], &sm[S_][0][l_row0][0]); \
    gld_lds16(&Bt[(size_t)(bn + g_row0) * K + (T_) * 32 + g_chk], &sm[S_][1][l_row0][0]); }

#define COMPUTE(S_) {                                                                    \
    bf16x8 af[2], bfr[4];                                                                \
    _Pragma("unroll")                                                                    \
    for (int m = 0; m < 2; ++m)                                                          \
        af[m] = *reinterpret_cast<const bf16x8*>(                                        \
            (const char*)&sm[S_][0][wr + m * 16 + ln_c][0] + colx);                      \
    _Pragma("unroll")                                                                    \
    for (int n = 0; n < 4; ++n)                                                          \
        bfr[n] = *reinterpret_cast<const bf16x8*>(                                       \
            (const char*)&sm[S_][1][wc + n * 16 + ln_c][0] + colx);                      \
    _Pragma("unroll")                                                                    \
    for (int m = 0; m < 2; ++m)                                                          \
        _Pragma("unroll")                                                                \
        for (int n = 0; n < 4; ++n)                                                      \
            acc[m][n] = __builtin_amdgcn_mfma_f32_16x16x32_bf16(af[m], bfr[n],           \
                                                                 acc[m][n], 0, 0, 0); }

#define WAITV2 { asm volatile("s_waitcnt vmcnt(2) lgkmcnt(0)" ::: "memory");             \
                 __builtin_amdgcn_s_barrier();                                           \
                 __builtin_amdgcn_sched_barrier(0); }
#define WAITV0 { asm volatile("s_waitcnt vmcnt(0) lgkmcnt(0)" ::: "memory");             \
                 __builtin_amdgcn_s_barrier();                                           \
                 __builtin_amdgcn_sched_barrier(0); }

    STAGE(0, 0);
    STAGE(1, 1);

    #pragma unroll 1
    for (int i = 0; i < 10; ++i) {
        const int t0 = i * 3;
        WAITV2; STAGE(2, t0 + 2); COMPUTE(0);
        WAITV2; STAGE(0, t0 + 3); COMPUTE(1);
        WAITV2; STAGE(1, t0 + 4); COMPUTE(2);
    }
    WAITV2; COMPUTE(0);
    WAITV0; COMPUTE(1);

#undef STAGE
#undef COMPUTE
#undef WAITV2
#undef WAITV0

    #pragma unroll
    for (int m = 0; m < 2; ++m) {
        #pragma unroll
        for (int n = 0; n < 4; ++n) {
            const int col = bn + wc + n * 16 + ln_c;
            const float bcol = bias[col];
            #pragma unroll
            for (int j = 0; j < 4; ++j) {
                const int row = bm + wr + m * 16 + ln_g * 4 + j;
                float v = acc[m][n][j] + bcol;
                if (MODE == 0) {
                    const int part = col >> 10;
                    const int cc = col & 1023;
                    const int h = cc >> 6, d = cc & 63;
                    const int b = row >> 11, t = row & 2047;
                    const int bh = b * H_ + h;
                    if (part == 0)
                        Qo[((size_t)bh * T_ + t) * HD_ + d] = __float2bfloat16(v * QSCALE);
                    else if (part == 1)
                        Ko[((size_t)bh * T_ + t) * HD_ + d] = __float2bfloat16(v);
                    else
                        Vo[((size_t)bh * HD_ + d) * T_ + t] = __float2bfloat16(v);
                } else {
                    Fo[(size_t)row * D_ + col] = v;
                }
            }
        }
    }
}

// ---------------------------------------------------------------- causal flash attention v5
// v4b + KVBLK=128: halves iteration count / barriers / per-iter bookkeeping.
// Ks[128][72] + Vs[64][136] = 35.8 KB -> 4 blocks/CU. st[8], 8-int4 staging
// (~115 VGPR, cap 128 via launch_bounds(256,4)). nk2 = (qt+2)>>1; mask on last
// tile only (covers diagonal + fully-masked upper half on even qt).
__global__ __launch_bounds__(256, 4)
void attn_kernel(const bf16* __restrict__ Q, const bf16* __restrict__ K,
                 const bf16* __restrict__ Vt, bf16* __restrict__ ctx) {
    const int bh = blockIdx.x & 63;
    const int qt = 31 - (blockIdx.x >> 6);   // longest blocks first
    const int tid  = threadIdx.x;
    const int wave = tid >> 6;
    const int lane = tid & 63;
    const int ln_g = lane >> 4;
    const int ln_c = lane & 15;

    const bf16* Qp = Q  + (size_t)bh * T_ * HD_;
    const bf16* Kp = K  + (size_t)bh * T_ * HD_;
    const bf16* Vp = Vt + (size_t)bh * HD_ * T_;

    __shared__ bf16 Ks[128][72];
    __shared__ bf16 Vs[64][136];

    // K staging: 128 rows x 64 cols; 4 rounds of (row tid>>3 + 32j, col (tid&7)*8)
    const int krow = tid >> 3;
    const int kc8  = (tid & 7) * 8;
    // V staging: 64 rows x 128 cols; 4 rounds of (row tid>>4 + 16j, col (tid&15)*8)
    const int vrow = tid >> 4;
    const int vc8  = (tid & 15) * 8;

    const int b = bh >> 4, h = bh & 15;

    const int qbase = qt * 64;
    const int qglob = qbase + wave * 16 + ln_c;

    const bf16x8 qf0 = *reinterpret_cast<const bf16x8*>(&Qp[(size_t)qglob * HD_ + ln_g * 8]);
    const bf16x8 qf1 = *reinterpret_cast<const bf16x8*>(&Qp[(size_t)qglob * HD_ + 32 + ln_g * 8]);

    f32x4 o[4] = {};
    float m = -INFINITY, l = 0.f;

    const int nk2 = (qt + 2) >> 1;          // 128-wide kv tiles

    int4 kr0, kr1, kr2, kr3, vr0, vr1, vr2, vr3;
    kr0 = *reinterpret_cast<const int4*>(&Kp[(size_t)(krow)      * HD_ + kc8]);
    kr1 = *reinterpret_cast<const int4*>(&Kp[(size_t)(krow + 32) * HD_ + kc8]);
    kr2 = *reinterpret_cast<const int4*>(&Kp[(size_t)(krow + 64) * HD_ + kc8]);
    kr3 = *reinterpret_cast<const int4*>(&Kp[(size_t)(krow + 96) * HD_ + kc8]);
    vr0 = *reinterpret_cast<const int4*>(&Vp[(size_t)(vrow)      * T_ + vc8]);
    vr1 = *reinterpret_cast<const int4*>(&Vp[(size_t)(vrow + 16) * T_ + vc8]);
    vr2 = *reinterpret_cast<const int4*>(&Vp[(size_t)(vrow + 32) * T_ + vc8]);
    vr3 = *reinterpret_cast<const int4*>(&Vp[(size_t)(vrow + 48) * T_ + vc8]);
    *reinterpret_cast<int4*>(&Ks[krow][kc8])       = kr0;
    *reinterpret_cast<int4*>(&Ks[krow + 32][kc8])  = kr1;
    *reinterpret_cast<int4*>(&Ks[krow + 64][kc8])  = kr2;
    *reinterpret_cast<int4*>(&Ks[krow + 96][kc8])  = kr3;
    *reinterpret_cast<int4*>(&Vs[vrow][vc8])       = vr0;
    *reinterpret_cast<int4*>(&Vs[vrow + 16][vc8])  = vr1;
    *reinterpret_cast<int4*>(&Vs[vrow + 32][vc8])  = vr2;
    *reinterpret_cast<int4*>(&Vs[vrow + 48][vc8])  = vr3;
    __syncthreads();

    for (int it = 0; it < nk2; ++it) {
        const int kb = it * 128;
        const bool notlast = (it + 1 < nk2);
        if (notlast) {   // async-stage split: issue next tile's loads now
            const int kn = kb + 128;
            kr0 = *reinterpret_cast<const int4*>(&Kp[(size_t)(kn + krow)      * HD_ + kc8]);
            kr1 = *reinterpret_cast<const int4*>(&Kp[(size_t)(kn + krow + 32) * HD_ + kc8]);
            kr2 = *reinterpret_cast<const int4*>(&Kp[(size_t)(kn + krow + 64) * HD_ + kc8]);
            kr3 = *reinterpret_cast<const int4*>(&Kp[(size_t)(kn + krow + 96) * HD_ + kc8]);
            vr0 = *reinterpret_cast<const int4*>(&Vp[(size_t)(vrow)      * T_ + kn + vc8]);
            vr1 = *reinterpret_cast<const int4*>(&Vp[(size_t)(vrow + 16) * T_ + kn + vc8]);
            vr2 = *reinterpret_cast<const int4*>(&Vp[(size_t)(vrow + 32) * T_ + kn + vc8]);
            vr3 = *reinterpret_cast<const int4*>(&Vp[(size_t)(vrow + 48) * T_ + kn + vc8]);
        }

        // ---- S^T = K Q^T : st[kk][j] <-> k = kb + kk*16 + ln_g*4 + j
        f32x4 st[8];
        __builtin_amdgcn_s_setprio(1);
        #pragma unroll
        for (int kk = 0; kk < 8; ++kk) {
            bf16x8 kfa = *reinterpret_cast<const bf16x8*>(&Ks[kk * 16 + ln_c][ln_g * 8]);
            bf16x8 kfb = *reinterpret_cast<const bf16x8*>(&Ks[kk * 16 + ln_c][32 + ln_g * 8]);
            f32x4 z = {0.f, 0.f, 0.f, 0.f};
            z = __builtin_amdgcn_mfma_f32_16x16x32_bf16(kfa, qf0, z, 0, 0, 0);
            z = __builtin_amdgcn_mfma_f32_16x16x32_bf16(kfb, qf1, z, 0, 0, 0);
            st[kk] = z;
        }
        __builtin_amdgcn_s_setprio(0);

        if (!notlast) {   // last tile: causal mask (diagonal + any over-extent)
            #pragma unroll
            for (int kk = 0; kk < 8; ++kk)
                #pragma unroll
                for (int j = 0; j < 4; ++j)
                    if (kb + kk * 16 + ln_g * 4 + j > qglob) st[kk][j] = -INFINITY;
        }

        // ---- per-lane local max; shuffle-free defer check (rescale is rare)
        float mx = -INFINITY;
        #pragma unroll
        for (int kk = 0; kk < 8; ++kk)
            #pragma unroll
            for (int j = 0; j < 4; ++j)
                mx = fmaxf(mx, st[kk][j]);
        if (!__all(mx - m <= 8.f)) {
            float r = fmaxf(mx, __shfl_xor(mx, 16));
            r = fmaxf(r, __shfl_xor(r, 32));
            const float mnew = fmaxf(m, r);
            const float alpha = exp2f(m - mnew);
            l *= alpha;
            #pragma unroll
            for (int dt = 0; dt < 4; ++dt)
                #pragma unroll
                for (int j = 0; j < 4; ++j)
                    o[dt][j] *= alpha;
            m = mnew;
        }

        // ---- P = exp2(S - m) packed in-register; PV via mfma16 (P never in LDS)
        #pragma unroll
        for (int kk = 0; kk < 8; ++kk) {
            float p0 = exp2f(st[kk][0] - m);
            float p1 = exp2f(st[kk][1] - m);
            float p2 = exp2f(st[kk][2] - m);
            float p3 = exp2f(st[kk][3] - m);
            l += (p0 + p1) + (p2 + p3);
            uint2 pw;
            pw.x = bfbits(p0) | (bfbits(p1) << 16);
            pw.y = bfbits(p2) | (bfbits(p3) << 16);
            const s16x4 ps = __builtin_bit_cast(s16x4, pw);
            __builtin_amdgcn_s_setprio(1);
            #pragma unroll
            for (int dt = 0; dt < 4; ++dt) {
                s16x4 vf = *reinterpret_cast<const s16x4*>(
                    &Vs[dt * 16 + ln_c][kk * 16 + ln_g * 4]);
                o[dt] = mfma16(vf, ps, o[dt]);
            }
            __builtin_amdgcn_s_setprio(0);
        }

        if (notlast) {
            __syncthreads();
            *reinterpret_cast<int4*>(&Ks[krow][kc8])       = kr0;
            *reinterpret_cast<int4*>(&Ks[krow + 32][kc8])  = kr1;
            *reinterpret_cast<int4*>(&Ks[krow + 64][kc8])  = kr2;
            *reinterpret_cast<int4*>(&Ks[krow + 96][kc8])  = kr3;
            *reinterpret_cast<int4*>(&Vs[vrow][vc8])       = vr0;
            *reinterpret_cast<int4*>(&Vs[vrow + 16][vc8])  = vr1;
            *reinterpret_cast<int4*>(&Vs[vrow + 32][vc8])  = vr2;
            *reinterpret_cast<int4*>(&Vs[vrow + 48][vc8])  = vr3;
            __syncthreads();
        }
    }

    // ---- epilogue
    l += __shfl_xor(l, 16);
    l += __shfl_xor(l, 32);
    const float inv = 1.0f / l;
    bf16* dst = ctx + ((size_t)(b * T_ + qglob)) * D_ + h * HD_;
    #pragma unroll
    for (int dt = 0; dt < 4; ++dt) {
        union { bf16 hh[4]; uint2 u; } ok;
        #pragma unroll
        for (int j = 0; j < 4; ++j)
            ok.hh[j] = __float2bfloat16(o[dt][j] * inv);
        *reinterpret_cast<uint2*>(&dst[dt * 16 + ln_g * 4]) = ok.u;
    }
}

// ---------------------------------------------------------------- launch
extern "C" void kernel_launch(void* const* d_in, const int* in_sizes, int n_in,
                              void* d_out, int out_size, void* d_ws, size_t ws_size,
                              hipStream_t stream) {
    const float* x      = (const float*)d_in[0];
    const float* W_attn = (const float*)d_in[1];
    const float* b_attn = (const float*)d_in[2];
    const float* W_proj = (const float*)d_in[3];
    const float* b_proj = (const float*)d_in[4];
    float* out = (float*)d_out;

    char* ws = (char*)d_ws;
    bf16* xh  = (bf16*)ws;  ws += (size_t)BT_ * D_ * 2;
    bf16* WaT = (bf16*)ws;  ws += (size_t)3 * D_ * D_ * 2;
    bf16* WpT = (bf16*)ws;  ws += (size_t)D_ * D_ * 2;
    bf16* Qb  = (bf16*)ws;  ws += (size_t)BH_ * T_ * HD_ * 2;
    bf16* Kb  = (bf16*)ws;  ws += (size_t)BH_ * T_ * HD_ * 2;
    bf16* Vb  = (bf16*)ws;  ws += (size_t)BH_ * T_ * HD_ * 2;
    bf16* ctx = (bf16*)ws;  ws += (size_t)BT_ * D_ * 2;

    prep_kernel<<<8192, 256, 0, stream>>>(x, W_attn, W_proj, xh, WaT, WpT);

    gemm_bt<0><<<dim3(BT_ / 128, 3 * D_ / 128), 512, 0, stream>>>(
        xh, WaT, b_attn, Qb, Kb, Vb, nullptr);

    attn_kernel<<<dim3(BH_ * 32), 256, 0, stream>>>(Qb, Kb, Vb, ctx);

    gemm_bt<1><<<dim3(BT_ / 128, D_ / 128), 512, 0, stream>>>(
        ctx, WpT, b_proj, nullptr, nullptr, nullptr, out);
}

// Round 21
// 176.097 us; speedup vs baseline: 1.0261x; 1.0261x over previous
//
#include <hip/hip_runtime.h>
#include <hip/hip_bf16.h>

using bf16 = __hip_bfloat16;
typedef __attribute__((ext_vector_type(8))) __bf16 bf16x8;
typedef __attribute__((ext_vector_type(4))) short s16x4;
typedef __attribute__((ext_vector_type(4))) float f32x4;

#define B_   4
#define T_   2048
#define D_   1024
#define H_   16
#define HD_  64
#define BH_  (B_ * H_)
#define BT_  (B_ * T_)

// Q pre-scale: 1/sqrt(64) * log2(e)  -> softmax computed with exp2
#define QSCALE 0.18033688011112042f

__device__ __forceinline__ void gld_lds16(const void* g, void* l) {
    __builtin_amdgcn_global_load_lds(
        (const __attribute__((address_space(1))) unsigned int*)g,
        (__attribute__((address_space(3))) unsigned int*)l,
        16, 0, 0);
}

__device__ __forceinline__ f32x4 mfma16(s16x4 a, s16x4 b, f32x4 c) {
#if defined(__HIP_DEVICE_COMPILE__)
  #if __has_builtin(__builtin_amdgcn_mfma_f32_16x16x16bf16_1k)
    return __builtin_amdgcn_mfma_f32_16x16x16bf16_1k(a, b, c, 0, 0, 0);
  #else
    f32x4 d;
    asm volatile("v_mfma_f32_16x16x16_bf16 %0, %1, %2, %3\n\ts_nop 7\n\ts_nop 7"
                 : "=v"(d) : "v"(a), "v"(b), "v"(c));
    return d;
  #endif
#else
    (void)a; (void)b;
    return c;
#endif
}

__device__ __forceinline__ unsigned bfbits(float x) {
    return (unsigned)__builtin_bit_cast(unsigned short, __float2bfloat16(x));
}

// ---------------------------------------------------------------- fused prep (frozen)
__global__ __launch_bounds__(256)
void prep_kernel(const float* __restrict__ x,
                 const float* __restrict__ W_attn,
                 const float* __restrict__ W_proj,
                 bf16* __restrict__ xh, bf16* __restrict__ WaT, bf16* __restrict__ WpT) {
    __shared__ float tile[32][33];
    const int blk = blockIdx.x;
    const int tid = threadIdx.x;

    if (blk < 4096) {
        const size_t i = ((size_t)blk * 256 + tid) * 8;
        float4 v0 = *reinterpret_cast<const float4*>(x + i);
        float4 v1 = *reinterpret_cast<const float4*>(x + i + 4);
        uint4 p;
        p.x = bfbits(v0.x) | (bfbits(v0.y) << 16);
        p.y = bfbits(v0.z) | (bfbits(v0.w) << 16);
        p.z = bfbits(v1.x) | (bfbits(v1.y) << 16);
        p.w = bfbits(v1.z) | (bfbits(v1.w) << 16);
        *reinterpret_cast<uint4*>(xh + i) = p;
        return;
    }

    if (blk < 4096 + 3072) {
        const int t = blk - 4096;
        const int nb = (t % 96) * 32, kb = (t / 96) * 32;
        const int tx = tid & 31, ty = tid >> 5;
        #pragma unroll
        for (int i = 0; i < 32; i += 8)
            tile[ty + i][tx] = W_attn[(size_t)(kb + ty + i) * 3072 + nb + tx];
        __syncthreads();
        #pragma unroll
        for (int i = 0; i < 32; i += 8)
            WaT[(size_t)(nb + ty + i) * 1024 + kb + tx] = __float2bfloat16(tile[tx][ty + i]);
    } else {
        const int t = blk - 4096 - 3072;
        const int nb = (t % 32) * 32, kb = (t / 32) * 32;
        const int tx = tid & 31, ty = tid >> 5;
        #pragma unroll
        for (int i = 0; i < 32; i += 8)
            tile[ty + i][tx] = W_proj[(size_t)(kb + ty + i) * 1024 + nb + tx];
        __syncthreads();
        #pragma unroll
        for (int i = 0; i < 32; i += 8)
            WpT[(size_t)(nb + ty + i) * 1024 + kb + tx] = __float2bfloat16(tile[tx][ty + i]);
    }
}

// ---------------------------------------------------------------- GEMM  C = A @ Bt^T (+bias)
// 128x128 tile, K=1024, BK=32, ring-3 LDS (48 KB), counted vmcnt; 8 waves (512 thr),
// per-wave 32x64 C (acc[2][4]) -> 6 waves/SIMD chain-hiding. Stage = 2 DMA calls;
// counted waits vmcnt(2)/vmcnt(0). XOR-swizzled LDS (0-conflict verified).
// MODE 0: QKV scatter. MODE 1: fp32 + bias.
template <int MODE>
__global__ __launch_bounds__(512)
void gemm_bt(const bf16* __restrict__ A, const bf16* __restrict__ Bt,
             const float* __restrict__ bias,
             bf16* __restrict__ Qo, bf16* __restrict__ Ko, bf16* __restrict__ Vo,
             float* __restrict__ Fo) {
    constexpr int K = 1024;
    const int bm = blockIdx.x * 128;
    const int bn = blockIdx.y * 128;
    const int tid  = threadIdx.x;
    const int wid  = tid >> 6;          // 0..7
    const int lane = tid & 63;
    const int wr = (wid >> 1) * 32;     // 4 M-rows of 32
    const int wc = (wid & 1) * 64;      // 2 N-cols of 64
    const int ln_g = lane >> 4;         // 0..3
    const int ln_c = lane & 15;         // 0..15

    __shared__ bf16 sm[3][2][128][32];  // ring-3: [slot][A/B][row][col]

    f32x4 acc[2][4] = {};

    const int g_row0 = wid * 16 + (lane >> 2);               // 0..127
    const int g_chk  = ((lane & 3) ^ ((lane >> 3) & 3)) * 8; // pre-swizzled elem off
    const int l_row0 = wid * 16;                             // wave-uniform LDS row base
    const int colx = (ln_g * 16) ^ (((ln_c >> 1) & 3) << 4); // read-side swizzle

#define STAGE(S_, T_) {                                                               \
    gld_lds16(&A [(size_t)(bm + g_row0) * K + (T_) * 32 + g_chk], &sm[S_][0][l_row0][0]); \
    gld_lds16(&Bt[(size_t)(bn + g_row0) * K + (T_) * 32 + g_chk], &sm[S_][1][l_row0][0]); }

#define COMPUTE(S_) {                                                                    \
    bf16x8 af[2], bfr[4];                                                                \
    _Pragma("unroll")                                                                    \
    for (int m = 0; m < 2; ++m)                                                          \
        af[m] = *reinterpret_cast<const bf16x8*>(                                        \
            (const char*)&sm[S_][0][wr + m * 16 + ln_c][0] + colx);                      \
    _Pragma("unroll")                                                                    \
    for (int n = 0; n < 4; ++n)                                                          \
        bfr[n] = *reinterpret_cast<const bf16x8*>(                                       \
            (const char*)&sm[S_][1][wc + n * 16 + ln_c][0] + colx);                      \
    _Pragma("unroll")                                                                    \
    for (int m = 0; m < 2; ++m)                                                          \
        _Pragma("unroll")                                                                \
        for (int n = 0; n < 4; ++n)                                                      \
            acc[m][n] = __builtin_amdgcn_mfma_f32_16x16x32_bf16(af[m], bfr[n],           \
                                                                 acc[m][n], 0, 0, 0); }

#define WAITV2 { asm volatile("s_waitcnt vmcnt(2) lgkmcnt(0)" ::: "memory");             \
                 __builtin_amdgcn_s_barrier();                                           \
                 __builtin_amdgcn_sched_barrier(0); }
#define WAITV0 { asm volatile("s_waitcnt vmcnt(0) lgkmcnt(0)" ::: "memory");             \
                 __builtin_amdgcn_s_barrier();                                           \
                 __builtin_amdgcn_sched_barrier(0); }

    STAGE(0, 0);
    STAGE(1, 1);

    // 30 tiles in 10 triples; per triple i: stage tiles 3i+2,3i+3,3i+4 (slot t%3),
    // compute tiles 3i,3i+1,3i+2.  (R13 induction; 2 calls/stage -> vmcnt(2).)
    #pragma unroll 1
    for (int i = 0; i < 10; ++i) {
        const int t0 = i * 3;
        WAITV2; STAGE(2, t0 + 2); COMPUTE(0);
        WAITV2; STAGE(0, t0 + 3); COMPUTE(1);
        WAITV2; STAGE(1, t0 + 4); COMPUTE(2);
    }
    WAITV2; COMPUTE(0);   // tile 30 (tile 31's stage in flight)
    WAITV0; COMPUTE(1);   // tile 31

#undef STAGE
#undef COMPUTE
#undef WAITV2
#undef WAITV0

    #pragma unroll
    for (int m = 0; m < 2; ++m) {
        #pragma unroll
        for (int n = 0; n < 4; ++n) {
            const int col = bn + wc + n * 16 + ln_c;
            const float bcol = bias[col];
            #pragma unroll
            for (int j = 0; j < 4; ++j) {
                const int row = bm + wr + m * 16 + ln_g * 4 + j;
                float v = acc[m][n][j] + bcol;
                if (MODE == 0) {
                    const int part = col >> 10;       // 0=q 1=k 2=v
                    const int cc = col & 1023;
                    const int h = cc >> 6, d = cc & 63;
                    const int b = row >> 11, t = row & 2047;
                    const int bh = b * H_ + h;
                    if (part == 0)
                        Qo[((size_t)bh * T_ + t) * HD_ + d] = __float2bfloat16(v * QSCALE);
                    else if (part == 1)
                        Ko[((size_t)bh * T_ + t) * HD_ + d] = __float2bfloat16(v);
                    else
                        Vo[((size_t)bh * HD_ + d) * T_ + t] = __float2bfloat16(v);
                } else {
                    Fo[(size_t)row * D_ + col] = v;
                }
            }
        }
    }
}

// ---------------------------------------------------------------- causal flash attention v4b
// (best verified: swapped-operand QK^T, register-direct PV via mfma16, shuffle-free
//  defer-max softmax, per-lane l, LPT grid; KVBLK=64)
__global__ __launch_bounds__(256, 4)
void attn_kernel(const bf16* __restrict__ Q, const bf16* __restrict__ K,
                 const bf16* __restrict__ Vt, bf16* __restrict__ ctx) {
    const int bh = blockIdx.x & 63;
    const int qt = 31 - (blockIdx.x >> 6);
    const int tid  = threadIdx.x;
    const int wave = tid >> 6;
    const int lane = tid & 63;
    const int ln_g = lane >> 4;
    const int ln_c = lane & 15;

    const bf16* Qp = Q  + (size_t)bh * T_ * HD_;
    const bf16* Kp = K  + (size_t)bh * T_ * HD_;
    const bf16* Vp = Vt + (size_t)bh * HD_ * T_;

    __shared__ bf16 Ks[64][72];
    __shared__ bf16 Vs[64][72];

    const int srow = tid >> 3;
    const int sc8  = (tid & 7) * 8;

    const int b = bh >> 4, h = bh & 15;

    const int qbase = qt * 64;
    const int qglob = qbase + wave * 16 + ln_c;

    const bf16x8 qf0 = *reinterpret_cast<const bf16x8*>(&Qp[(size_t)qglob * HD_ + ln_g * 8]);
    const bf16x8 qf1 = *reinterpret_cast<const bf16x8*>(&Qp[(size_t)qglob * HD_ + 32 + ln_g * 8]);

    f32x4 o[4] = {};
    float m = -INFINITY, l = 0.f;

    const int nk = qt + 1;

    int4 kr0, kr1, vr0, vr1;
    kr0 = *reinterpret_cast<const int4*>(&Kp[(size_t)srow * HD_ + sc8]);
    kr1 = *reinterpret_cast<const int4*>(&Kp[(size_t)(srow + 32) * HD_ + sc8]);
    vr0 = *reinterpret_cast<const int4*>(&Vp[(size_t)srow * T_ + sc8]);
    vr1 = *reinterpret_cast<const int4*>(&Vp[(size_t)(srow + 32) * T_ + sc8]);
    *reinterpret_cast<int4*>(&Ks[srow][sc8])      = kr0;
    *reinterpret_cast<int4*>(&Ks[srow + 32][sc8]) = kr1;
    *reinterpret_cast<int4*>(&Vs[srow][sc8])      = vr0;
    *reinterpret_cast<int4*>(&Vs[srow + 32][sc8]) = vr1;
    __syncthreads();

    for (int it = 0; it < nk; ++it) {
        const int kb = it * 64;
        const bool notlast = (it + 1 < nk);
        if (notlast) {
            const int kn = kb + 64;
            kr0 = *reinterpret_cast<const int4*>(&Kp[(size_t)(kn + srow) * HD_ + sc8]);
            kr1 = *reinterpret_cast<const int4*>(&Kp[(size_t)(kn + srow + 32) * HD_ + sc8]);
            vr0 = *reinterpret_cast<const int4*>(&Vp[(size_t)srow * T_ + kn + sc8]);
            vr1 = *reinterpret_cast<const int4*>(&Vp[(size_t)(srow + 32) * T_ + kn + sc8]);
        }

        f32x4 st[4];
        __builtin_amdgcn_s_setprio(1);
        #pragma unroll
        for (int kk = 0; kk < 4; ++kk) {
            bf16x8 kfa = *reinterpret_cast<const bf16x8*>(&Ks[kk * 16 + ln_c][ln_g * 8]);
            bf16x8 kfb = *reinterpret_cast<const bf16x8*>(&Ks[kk * 16 + ln_c][32 + ln_g * 8]);
            f32x4 z = {0.f, 0.f, 0.f, 0.f};
            z = __builtin_amdgcn_mfma_f32_16x16x32_bf16(kfa, qf0, z, 0, 0, 0);
            z = __builtin_amdgcn_mfma_f32_16x16x32_bf16(kfb, qf1, z, 0, 0, 0);
            st[kk] = z;
        }
        __builtin_amdgcn_s_setprio(0);

        if (!notlast) {
            #pragma unroll
            for (int kk = 0; kk < 4; ++kk)
                #pragma unroll
                for (int j = 0; j < 4; ++j)
                    if (kb + kk * 16 + ln_g * 4 + j > qglob) st[kk][j] = -INFINITY;
        }

        float mx = -INFINITY;
        #pragma unroll
        for (int kk = 0; kk < 4; ++kk)
            #pragma unroll
            for (int j = 0; j < 4; ++j)
                mx = fmaxf(mx, st[kk][j]);
        if (!__all(mx - m <= 8.f)) {
            float r = fmaxf(mx, __shfl_xor(mx, 16));
            r = fmaxf(r, __shfl_xor(r, 32));
            const float mnew = fmaxf(m, r);
            const float alpha = exp2f(m - mnew);
            l *= alpha;
            #pragma unroll
            for (int dt = 0; dt < 4; ++dt)
                #pragma unroll
                for (int j = 0; j < 4; ++j)
                    o[dt][j] *= alpha;
            m = mnew;
        }

        #pragma unroll
        for (int kk = 0; kk < 4; ++kk) {
            float p0 = exp2f(st[kk][0] - m);
            float p1 = exp2f(st[kk][1] - m);
            float p2 = exp2f(st[kk][2] - m);
            float p3 = exp2f(st[kk][3] - m);
            l += (p0 + p1) + (p2 + p3);
            uint2 pw;
            pw.x = bfbits(p0) | (bfbits(p1) << 16);
            pw.y = bfbits(p2) | (bfbits(p3) << 16);
            const s16x4 ps = __builtin_bit_cast(s16x4, pw);
            __builtin_amdgcn_s_setprio(1);
            #pragma unroll
            for (int dt = 0; dt < 4; ++dt) {
                s16x4 vf = *reinterpret_cast<const s16x4*>(
                    &Vs[dt * 16 + ln_c][kk * 16 + ln_g * 4]);
                o[dt] = mfma16(vf, ps, o[dt]);
            }
            __builtin_amdgcn_s_setprio(0);
        }

        if (notlast) {
            __syncthreads();
            *reinterpret_cast<int4*>(&Ks[srow][sc8])      = kr0;
            *reinterpret_cast<int4*>(&Ks[srow + 32][sc8]) = kr1;
            *reinterpret_cast<int4*>(&Vs[srow][sc8])      = vr0;
            *reinterpret_cast<int4*>(&Vs[srow + 32][sc8]) = vr1;
            __syncthreads();
        }
    }

    l += __shfl_xor(l, 16);
    l += __shfl_xor(l, 32);
    const float inv = 1.0f / l;
    bf16* dst = ctx + ((size_t)(b * T_ + qglob)) * D_ + h * HD_;
    #pragma unroll
    for (int dt = 0; dt < 4; ++dt) {
        union { bf16 hh[4]; uint2 u; } ok;
        #pragma unroll
        for (int j = 0; j < 4; ++j)
            ok.hh[j] = __float2bfloat16(o[dt][j] * inv);
        *reinterpret_cast<uint2*>(&dst[dt * 16 + ln_g * 4]) = ok.u;
    }
}

// ---------------------------------------------------------------- launch
extern "C" void kernel_launch(void* const* d_in, const int* in_sizes, int n_in,
                              void* d_out, int out_size, void* d_ws, size_t ws_size,
                              hipStream_t stream) {
    const float* x      = (const float*)d_in[0];
    const float* W_attn = (const float*)d_in[1];
    const float* b_attn = (const float*)d_in[2];
    const float* W_proj = (const float*)d_in[3];
    const float* b_proj = (const float*)d_in[4];
    float* out = (float*)d_out;

    char* ws = (char*)d_ws;
    bf16* xh  = (bf16*)ws;  ws += (size_t)BT_ * D_ * 2;
    bf16* WaT = (bf16*)ws;  ws += (size_t)3 * D_ * D_ * 2;
    bf16* WpT = (bf16*)ws;  ws += (size_t)D_ * D_ * 2;
    bf16* Qb  = (bf16*)ws;  ws += (size_t)BH_ * T_ * HD_ * 2;
    bf16* Kb  = (bf16*)ws;  ws += (size_t)BH_ * T_ * HD_ * 2;
    bf16* Vb  = (bf16*)ws;  ws += (size_t)BH_ * T_ * HD_ * 2;
    bf16* ctx = (bf16*)ws;  ws += (size_t)BT_ * D_ * 2;

    prep_kernel<<<8192, 256, 0, stream>>>(x, W_attn, W_proj, xh, WaT, WpT);

    gemm_bt<0><<<dim3(BT_ / 128, 3 * D_ / 128), 512, 0, stream>>>(
        xh, WaT, b_attn, Qb, Kb, Vb, nullptr);

    attn_kernel<<<dim3(BH_ * 32), 256, 0, stream>>>(Qb, Kb, Vb, ctx);

    gemm_bt<1><<<dim3(BT_ / 128, D_ / 128), 512, 0, stream>>>(
        ctx, WpT, b_proj, nullptr, nullptr, nullptr, out);
}